// Round 3
// baseline (3556.902 us; speedup 1.0000x reference)
//
#include <hip/hip_runtime.h>

#define HS 256
#define NOUTC 4
#define NSTEPS 64
#define BATCH 4096

// h-state LDS row stride: 528 B (528 % 128 == 16) staggers bank alignment per
// row -> ds_read_b128 A-frag reads hit minimum aliasing, no XOR swizzle needed.
#define HROW 528

typedef _Float16 half8 __attribute__((ext_vector_type(8)));
typedef float floatx4 __attribute__((ext_vector_type(4)));

__device__ __forceinline__ float sigmoid_(float x) {
  return __builtin_amdgcn_rcpf(1.f + __expf(-x));
}
__device__ __forceinline__ float tanh_(float x) {
  float e = __expf(-2.f * fabsf(x));
  return copysignf((1.f - e) * __builtin_amdgcn_rcpf(1.f + e), x);
}

// Pre-swizzle the three [768][256] fp32 matrices into f16 MFMA-B-fragment order:
// chunk index = ((gm*48 + nt)*8 + kc)*64 + lane, 8 f16 per chunk:
//   value j = W[nt*16 + (lane&15)][kc*32 + (lane>>4)*8 + j]
__global__ __launch_bounds__(512) void prep_weights(
    const float* __restrict__ Whh0, const float* __restrict__ Wih1,
    const float* __restrict__ Whh1, _Float16* __restrict__ wfrag) {
  int id = blockIdx.x * 512 + threadIdx.x;  // 0..73727 (=3*48*8*64)
  int l = id & 63;
  int rest = id >> 6;
  int kc = rest & 7;
  int tile = rest >> 3;        // gm*48 + nt
  int gm = tile / 48;
  int nt = tile - gm * 48;
  const float* W = (gm == 0) ? Whh0 : ((gm == 1) ? Wih1 : Whh1);
  int row = nt * 16 + (l & 15);
  int k0 = kc * 32 + (l >> 4) * 8;
  const float* src = W + row * 256 + k0;
  _Float16* dst = wfrag + (size_t)id * 8;
#pragma unroll
  for (int j = 0; j < 8; ++j) dst[j] = (_Float16)src[j];
}

template <int GM>
__device__ __forceinline__ void gemm6(const half8* __restrict__ wf, int wv, int l,
                                      const half8 (&afr)[8], floatx4 (&acc)[6]) {
#pragma unroll
  for (int i = 0; i < 6; ++i) {
    const int g = i >> 1, s = i & 1;
    const int nt = g * 16 + wv * 2 + s;
    const half8* bp = wf + ((GM * 48 + nt) * 8) * 64 + l;
#pragma unroll
    for (int kc = 0; kc < 8; ++kc)
      acc[i] = __builtin_amdgcn_mfma_f32_16x16x32_f16(afr[kc], bp[kc * 64], acc[i], 0, 0, 0);
  }
}

__global__ __launch_bounds__(512) void gru_main(
    const float* __restrict__ inputs, const float* __restrict__ W_ih0,
    const float* __restrict__ b_ih0, const float* __restrict__ b_hh0,
    const float* __restrict__ b_ih1, const float* __restrict__ b_hh1,
    const float* __restrict__ W_out, const float* __restrict__ b_out,
    const _Float16* __restrict__ wfrag, float* __restrict__ out_outputs,
    float* __restrict__ out_hidden, float* __restrict__ out_probs,
    float* __restrict__ out_loss) {
  __shared__ __align__(16) unsigned char h0buf[16 * HROW];  // [16 rows][256 f16], stride 528B
  __shared__ __align__(16) unsigned char h1buf[16 * HROW];
  __shared__ float wout_lds[4 * 256];
  __shared__ float x_lds[2][64];
  __shared__ float tg_lds[2][64];
  __shared__ float loss_lds[16];

  const int tid = threadIdx.x;
  const int wv = tid >> 6;       // wave 0..7 -> h-dim range [wv*32, wv*32+32)
  const int l = tid & 63;
  const int l15 = l & 15, lq = l >> 4;
  const int rowbase = blockIdx.x * 16;
  const half8* __restrict__ wf = (const half8*)wfrag;

  // stage W_out to LDS
  for (int i = tid; i < 1024; i += 512) wout_lds[i] = W_out[i];
  // zero h buffers (f16 zeros)
  for (int i = tid * 16; i < 16 * HROW; i += 512 * 16) {
    *(floatx4*)(h0buf + i) = (floatx4){0.f, 0.f, 0.f, 0.f};
    *(floatx4*)(h1buf + i) = (floatx4){0.f, 0.f, 0.f, 0.f};
  }

  // hoisted per-lane constants: gate columns d_g = g*256 + wv*32 + s*16 + l15
  float bi0[3][2], bh0[3][2], bi1[3][2], bh1[3][2], wx[3][2][4];
  int dcol[2], cb2[2];
#pragma unroll
  for (int s = 0; s < 2; ++s) {
    dcol[s] = wv * 32 + s * 16 + l15;
    cb2[s] = dcol[s] * 2;
#pragma unroll
    for (int g = 0; g < 3; ++g) {
      int col = g * 256 + dcol[s];
      bi0[g][s] = b_ih0[col];
      bh0[g][s] = b_hh0[col];
      bi1[g][s] = b_ih1[col];
      bh1[g][s] = b_hh1[col];
#pragma unroll
      for (int c = 0; c < 4; ++c) wx[g][s][c] = W_ih0[col * 4 + c];
    }
  }
  const float bo0 = b_out[0], bo1 = b_out[1], bo2 = b_out[2], bo3 = b_out[3];

  float h0s[4][2] = {}, h1s[4][2] = {};
  float loss_acc = 0.f;

  // A-frag read base: row l15, byte = l15*528 + lq*16 (+ kc*64 immediate)
  const int abase = l15 * HROW + lq * 16;

  __syncthreads();

#pragma unroll 1
  for (int t = 0; t < NSTEPS; ++t) {
    const int par = t & 1;
    // stage x (=inputs[t-1], zeros at t==0) and target row inputs[t]
    if (tid < 64) {
      int r = tid >> 2, c = tid & 3;
      x_lds[par][tid] = (t > 0) ? inputs[((size_t)(t - 1) * BATCH + rowbase + r) * 4 + c] : 0.f;
    } else if (tid < 128) {
      int u = tid - 64;
      int r = u >> 2, c = u & 3;
      tg_lds[par][u] = inputs[((size_t)t * BATCH + rowbase + r) * 4 + c];
    }
    // read h0 A-frags (old h0) before barrier A
    half8 a0[8];
#pragma unroll
    for (int kc = 0; kc < 8; ++kc) a0[kc] = *(const half8*)(h0buf + abase + kc * 64);
    __syncthreads();  // barrier A

    // gh0 = h0 @ W_hh0^T
    floatx4 acc_h0[6] = {};
    gemm6<0>(wf, wv, l, a0, acc_h0);

    // read h1 A-frags, gh1 = h1 @ W_hh1^T
    half8 a1[8];
#pragma unroll
    for (int kc = 0; kc < 8; ++kc) a1[kc] = *(const half8*)(h1buf + abase + kc * 64);
    floatx4 acc_h1[6] = {};
    gemm6<2>(wf, wv, l, a1, acc_h1);

    // elementwise layer 0 -> h0n, write f16 frags to h0buf
#pragma unroll
    for (int j = 0; j < 4; ++j) {
      const int m = lq * 4 + j;
      const float x0 = x_lds[par][m * 4 + 0], x1 = x_lds[par][m * 4 + 1];
      const float x2 = x_lds[par][m * 4 + 2], x3 = x_lds[par][m * 4 + 3];
#pragma unroll
      for (int s = 0; s < 2; ++s) {
        float gir = bi0[0][s] + x0 * wx[0][s][0] + x1 * wx[0][s][1] + x2 * wx[0][s][2] + x3 * wx[0][s][3];
        float giz = bi0[1][s] + x0 * wx[1][s][0] + x1 * wx[1][s][1] + x2 * wx[1][s][2] + x3 * wx[1][s][3];
        float gin = bi0[2][s] + x0 * wx[2][s][0] + x1 * wx[2][s][1] + x2 * wx[2][s][2] + x3 * wx[2][s][3];
        float r = sigmoid_(gir + acc_h0[0 + s][j] + bh0[0][s]);
        float z = sigmoid_(giz + acc_h0[2 + s][j] + bh0[1][s]);
        float n = tanh_(gin + r * (acc_h0[4 + s][j] + bh0[2][s]));
        float hn = n + z * (h0s[j][s] - n);
        h0s[j][s] = hn;
        *(_Float16*)(h0buf + m * HROW + cb2[s]) = (_Float16)hn;
      }
    }
    __syncthreads();  // barrier B (h0n visible)

    // gi1 = h0n @ W_ih1^T
    half8 a0n[8];
#pragma unroll
    for (int kc = 0; kc < 8; ++kc) a0n[kc] = *(const half8*)(h0buf + abase + kc * 64);
    floatx4 acc_i1[6] = {};
    gemm6<1>(wf, wv, l, a0n, acc_i1);

    // elementwise layer 1 -> h1n, write frags + outputs
#pragma unroll
    for (int j = 0; j < 4; ++j) {
      const int m = lq * 4 + j;
#pragma unroll
      for (int s = 0; s < 2; ++s) {
        float r = sigmoid_(acc_i1[0 + s][j] + bi1[0][s] + acc_h1[0 + s][j] + bh1[0][s]);
        float z = sigmoid_(acc_i1[2 + s][j] + bi1[1][s] + acc_h1[2 + s][j] + bh1[1][s]);
        float n = tanh_(acc_i1[4 + s][j] + bi1[2][s] + r * (acc_h1[4 + s][j] + bh1[2][s]));
        float hn = n + z * (h1s[j][s] - n);
        h1s[j][s] = hn;
        *(_Float16*)(h1buf + m * HROW + cb2[s]) = (_Float16)hn;
        out_outputs[((size_t)t * BATCH + rowbase + m) * HS + dcol[s]] = hn;
      }
    }
    __syncthreads();  // barrier C (h1n visible)

    // loss / probs: 256 threads, 16 per row
    if (tid < 256) {
      const int row = tid >> 4, kch = tid & 15;
      const int cb = kch * 32;
      half8 p0 = *(const half8*)(h1buf + row * HROW + cb);
      half8 p1 = *(const half8*)(h1buf + row * HROW + cb + 16);
      float pt[4];
#pragma unroll
      for (int o = 0; o < 4; ++o) {
        const float* wo = wout_lds + o * 256 + kch * 16;
        float a = 0.f;
#pragma unroll
        for (int jj = 0; jj < 8; ++jj) a += (float)p0[jj] * wo[jj] + (float)p1[jj] * wo[8 + jj];
        pt[o] = a;
      }
#pragma unroll
      for (int sh = 1; sh < 16; sh <<= 1) {
#pragma unroll
        for (int o = 0; o < 4; ++o) pt[o] += __shfl_xor(pt[o], sh);
      }
      if ((tid & 15) == 0) {
        float lg0 = pt[0] + bo0, lg1 = pt[1] + bo1, lg2 = pt[2] + bo2, lg3 = pt[3] + bo3;
        float mx = fmaxf(fmaxf(lg0, lg1), fmaxf(lg2, lg3));
        float e0 = __expf(lg0 - mx), e1 = __expf(lg1 - mx);
        float e2 = __expf(lg2 - mx), e3 = __expf(lg3 - mx);
        float ssum = e0 + e1 + e2 + e3;
        float inv = __builtin_amdgcn_rcpf(ssum);
        floatx4 pr;
        pr[0] = e0 * inv; pr[1] = e1 * inv; pr[2] = e2 * inv; pr[3] = e3 * inv;
        *(floatx4*)(out_probs + ((size_t)t * BATCH + rowbase + row) * 4) = pr;
        float t0 = tg_lds[par][row * 4 + 0], t1 = tg_lds[par][row * 4 + 1];
        float t2 = tg_lds[par][row * 4 + 2], t3 = tg_lds[par][row * 4 + 3];
        float bv = t0, lt = lg0;
        if (t1 > bv) { bv = t1; lt = lg1; }
        if (t2 > bv) { bv = t2; lt = lg2; }
        if (t3 > bv) { bv = t3; lt = lg3; }
        loss_acc -= (lt - mx - __logf(ssum));
      }
    }
  }

  // final hidden states
#pragma unroll
  for (int j = 0; j < 4; ++j) {
    const int m = lq * 4 + j;
#pragma unroll
    for (int s = 0; s < 2; ++s) {
      out_hidden[(size_t)(rowbase + m) * HS + dcol[s]] = h0s[j][s];
      out_hidden[(size_t)BATCH * HS + (size_t)(rowbase + m) * HS + dcol[s]] = h1s[j][s];
    }
  }

  // loss reduction: 16 leaders (tid = 0,16,...,240)
  if (tid < 256 && (tid & 15) == 0) loss_lds[tid >> 4] = loss_acc;
  __syncthreads();
  if (tid == 0) {
    float s = 0.f;
#pragma unroll
    for (int i = 0; i < 16; ++i) s += loss_lds[i];
    atomicAdd(out_loss, s * (1.0f / 4096.0f));
  }
}

extern "C" void kernel_launch(void* const* d_in, const int* in_sizes, int n_in,
                              void* d_out, int out_size, void* d_ws, size_t ws_size,
                              hipStream_t stream) {
  (void)in_sizes; (void)n_in; (void)out_size; (void)ws_size;
  const float* inputs = (const float*)d_in[0];
  const float* W_ih0 = (const float*)d_in[1];
  const float* W_hh0 = (const float*)d_in[2];
  const float* b_ih0 = (const float*)d_in[3];
  const float* b_hh0 = (const float*)d_in[4];
  const float* W_ih1 = (const float*)d_in[5];
  const float* W_hh1 = (const float*)d_in[6];
  const float* b_ih1 = (const float*)d_in[7];
  const float* b_hh1 = (const float*)d_in[8];
  const float* W_out = (const float*)d_in[9];
  const float* b_out = (const float*)d_in[10];

  float* out = (float*)d_out;
  float* out_outputs = out;                                    // 64*4096*256
  float* out_hidden = out_outputs + (size_t)64 * 4096 * 256;   // 2*4096*256
  float* out_probs = out_hidden + (size_t)2 * 4096 * 256;      // 64*4096*4
  float* out_loss = out_probs + (size_t)64 * 4096 * 4;         // 1
  // inputX (= zeros) follows loss: zero both in one memset
  hipMemsetAsync(out_loss, 0, (size_t)(1 + 4096 * 4) * sizeof(float), stream);

  _Float16* wfrag = (_Float16*)d_ws;  // 3*48*8*64 chunks * 16B = 1.125 MiB
  prep_weights<<<144, 512, 0, stream>>>(W_hh0, W_ih1, W_hh1, wfrag);
  gru_main<<<256, 512, 0, stream>>>(inputs, W_ih0, b_ih0, b_hh0, b_ih1, b_hh1,
                                    W_out, b_out, wfrag, out_outputs, out_hidden,
                                    out_probs, out_loss);
}